// Round 13
// baseline (427.600 us; speedup 1.0000x reference)
//
#include <hip/hip_runtime.h>
#include <math.h>

#define E_EDGES 8192
#define D_FEAT 2048
#define K2 4096   // 2*D
#define H_DIM 128
#define N_NODES 100000
#define SIM_TH 0.7f
#define NSLOTS (2 * E_EDGES)   // 16384 compact slots
#define SORTN 8192
#define GBM 8                  // gate edges per block (v4)

// ---------------------------------------------------------------------------
// Kernel 1: cosine similarity per edge. One wave (64 lanes) per edge.
// ---------------------------------------------------------------------------
__global__ __launch_bounds__(256) void sim_kernel(const float* __restrict__ xf,
                                                  const float* __restrict__ yf,
                                                  float* __restrict__ sim) {
    int gid  = blockIdx.x * blockDim.x + threadIdx.x;
    int wave = gid >> 6;
    int lane = threadIdx.x & 63;
    if (wave >= E_EDGES) return;
    const float4* xp = (const float4*)(xf + (size_t)wave * D_FEAT);
    const float4* yp = (const float4*)(yf + (size_t)wave * D_FEAT);
    float dot = 0.f, xx = 0.f, yy = 0.f;
#pragma unroll
    for (int j = 0; j < 8; ++j) {
        float4 a = xp[lane + j * 64];
        float4 b = yp[lane + j * 64];
        dot += a.x * b.x + a.y * b.y + a.z * b.z + a.w * b.w;
        xx  += a.x * a.x + a.y * a.y + a.z * a.z + a.w * a.w;
        yy  += b.x * b.x + b.y * b.y + b.z * b.z + b.w * b.w;
    }
#pragma unroll
    for (int off = 32; off; off >>= 1) {
        dot += __shfl_xor(dot, off);
        xx  += __shfl_xor(xx, off);
        yy  += __shfl_xor(yy, off);
    }
    if (lane == 0) {
        float nx = fmaxf(sqrtf(xx), 1e-8f);
        float ny = fmaxf(sqrtf(yy), 1e-8f);
        sim[wave] = dot / (nx * ny);
    }
}

// ---------------------------------------------------------------------------
// Kernel 2: init fo (=INT_MAX), orig (=-1), zero w output.
// ---------------------------------------------------------------------------
__global__ void initmap_kernel(int* __restrict__ fo, int* __restrict__ orig,
                               float* __restrict__ wout) {
    int i = blockIdx.x * blockDim.x + threadIdx.x;
    if (i < N_NODES) fo[i] = 0x7FFFFFFF;
    if (i < NSLOTS)  orig[i] = -1;
    if (i < E_EDGES) wout[i] = 0.f;
}

// ---------------------------------------------------------------------------
// Kernel 3: claim compact slot = first occurrence index in x0,y0,x1,y1,...
// ---------------------------------------------------------------------------
__global__ void claim_kernel(const int* __restrict__ x_idx, const int* __restrict__ y_idx,
                             int* __restrict__ fo) {
    int i = blockIdx.x * blockDim.x + threadIdx.x;
    if (i >= NSLOTS) return;
    int e = i >> 1;
    int v = (i & 1) ? y_idx[e] : x_idx[e];
    atomicMin(&fo[v], i);
}

// ---------------------------------------------------------------------------
// Kernel 4: orig[slot] = node for claimed slots.
// ---------------------------------------------------------------------------
__global__ void orig_kernel(const int* __restrict__ x_idx, const int* __restrict__ y_idx,
                            const int* __restrict__ fo, int* __restrict__ orig) {
    int i = blockIdx.x * blockDim.x + threadIdx.x;
    if (i >= NSLOTS) return;
    int e = i >> 1;
    int v = (i & 1) ? y_idx[e] : x_idx[e];
    if (fo[v] == i) orig[i] = v;
}

// ---------------------------------------------------------------------------
// Kernel 5: order-preserving compaction of masked edges into records
//           rec = {cx, cy, eidx, (w filled later by gate)} + 4 zero pads.
// ---------------------------------------------------------------------------
__global__ __launch_bounds__(256) void maskscan_kernel(
        const int* __restrict__ x_idx, const int* __restrict__ y_idx,
        const int* __restrict__ fo, const float* __restrict__ sim,
        int4* __restrict__ rec, int* __restrict__ nmask) {
    __shared__ int partial[256];
    int t = threadIdx.x;
    int cnt = 0;
    for (int j = 0; j < 32; ++j) {
        int e = t * 32 + j;
        cnt += (sim[e] >= SIM_TH) ? 1 : 0;
    }
    partial[t] = cnt;
    __syncthreads();
    for (int off = 1; off < 256; off <<= 1) {
        int mine  = partial[t];
        int other = (t >= off) ? partial[t - off] : 0;
        __syncthreads();
        partial[t] = mine + other;
        __syncthreads();
    }
    int pos = partial[t] - cnt;
    if (t == 255) {
        int nn = partial[255];
        *nmask = nn;
        for (int j = 0; j < 4; ++j) rec[nn + j] = make_int4(0, 0, 0, 0);
    }
    for (int j = 0; j < 32; ++j) {
        int e = t * 32 + j;
        if (sim[e] >= SIM_TH) {
            int4 r;
            r.x = fo[x_idx[e]];
            r.y = fo[y_idx[e]];
            r.z = e;
            r.w = 0;
            rec[pos++] = r;
        }
    }
}

// ---------------------------------------------------------------------------
// Kernel 6: gate MLP v4 over MASKED edges. fp32 GEMM M=n, N=128, K=4096.
//   In-block K-split: waves 0-1 handle the x-half (k<2048), waves 2-3 the
//   y-half.  Each wave: 4 edges, lane = n column (n, n+64) -> A reads are
//   wave-uniform LDS broadcasts, B reads per-lane b32 on pitch-33 rows
//   (measured conflict-free).  GBM=8 -> 1024-block grid, 512 active ->
//   2 blocks/CU, 2 waves/SIMD (2x TLP vs v3).  Single-buffer LDS + register
//   prefetch (2 barriers/tile).  Partials combined in-LDS:
//   h = relu(p_lo + p_hi + b1), then the unchanged legacy-order W2 chain.
// ---------------------------------------------------------------------------
__global__ __launch_bounds__(256) void gate_kernel(
        const float* __restrict__ xf, const float* __restrict__ yf,
        const float* __restrict__ W1, const float* __restrict__ b1,
        const float* __restrict__ W2, const float* __restrict__ b2,
        int4* __restrict__ rec, const int* __restrict__ nmask,
        float* __restrict__ wout) {
    __shared__ float As[2][GBM][32];       //  2 KB   [half][edge][k]
    __shared__ float Bs[2][H_DIM][33];     // 33.8 KB [half][n][k] pitch 33
    __shared__ float hpart[2][GBM][132];   //  8.4 KB partial sums
    __shared__ int   elds[GBM];

    int n  = *nmask;
    int b0 = blockIdx.x * GBM;
    if (b0 >= n) return;

    int t = threadIdx.x;
    if (t < GBM) {
        int idx = b0 + t;
        elds[t] = (idx < n) ? rec[idx].z : rec[b0].z;
    }
    __syncthreads();

    // ---- staging assignments ----
    // A: threads 0..127 stage (half, edge, 4k): r = t>>3 in 0..15
    const int  ar   = t >> 3;
    const int  ah   = ar >> 3;             // half
    const int  ae   = ar & 7;              // edge
    const int  acol = (t & 7) * 4;
    const bool aact = (t < 128);
    // B: all threads stage 4 rows x 2 halves x 4k
    const int  brow = t >> 3;              // 0..31
    const int  bcol = (t & 7) * 4;

    const float* arow_p = (aact ? ((ah ? yf : xf) + (size_t)elds[ae] * D_FEAT + acol)
                                : (xf + (size_t)elds[0] * D_FEAT + acol));
    const float* w1p0 = W1 + (size_t)(brow +  0) * K2 + bcol;
    const float* w1p1 = W1 + (size_t)(brow + 32) * K2 + bcol;
    const float* w1p2 = W1 + (size_t)(brow + 64) * K2 + bcol;
    const float* w1p3 = W1 + (size_t)(brow + 96) * K2 + bcol;

    float4 aR;
    float4 bL0, bL1, bL2, bL3;   // half 0 (k offset +0)
    float4 bH0, bH1, bH2, bH3;   // half 1 (k offset +2048)

    // ---- prologue: load tile 0, store to LDS ----
    aR  = *(const float4*)(arow_p + 0);
    bL0 = *(const float4*)(w1p0 + 0);    bH0 = *(const float4*)(w1p0 + 2048);
    bL1 = *(const float4*)(w1p1 + 0);    bH1 = *(const float4*)(w1p1 + 2048);
    bL2 = *(const float4*)(w1p2 + 0);    bH2 = *(const float4*)(w1p2 + 2048);
    bL3 = *(const float4*)(w1p3 + 0);    bH3 = *(const float4*)(w1p3 + 2048);
    if (aact) *(float4*)(&As[ah][ae][acol]) = aR;
#define STB(hh, R0, R1, R2, R3)                                              \
    Bs[hh][brow +  0][bcol + 0] = R0.x; Bs[hh][brow +  0][bcol + 1] = R0.y;  \
    Bs[hh][brow +  0][bcol + 2] = R0.z; Bs[hh][brow +  0][bcol + 3] = R0.w;  \
    Bs[hh][brow + 32][bcol + 0] = R1.x; Bs[hh][brow + 32][bcol + 1] = R1.y;  \
    Bs[hh][brow + 32][bcol + 2] = R1.z; Bs[hh][brow + 32][bcol + 3] = R1.w;  \
    Bs[hh][brow + 64][bcol + 0] = R2.x; Bs[hh][brow + 64][bcol + 1] = R2.y;  \
    Bs[hh][brow + 64][bcol + 2] = R2.z; Bs[hh][brow + 64][bcol + 3] = R2.w;  \
    Bs[hh][brow + 96][bcol + 0] = R3.x; Bs[hh][brow + 96][bcol + 1] = R3.y;  \
    Bs[hh][brow + 96][bcol + 2] = R3.z; Bs[hh][brow + 96][bcol + 3] = R3.w;
    STB(0, bL0, bL1, bL2, bL3)
    STB(1, bH0, bH1, bH2, bH3)
    __syncthreads();

    const int half = t >> 7;             // wave's k-half
    const int eb   = ((t >> 6) & 1) * 4; // this wave's 4 edge rows
    const int ln   = t & 63;             // n = ln and ln+64
    float acc[4][2] = {{0.f,0.f},{0.f,0.f},{0.f,0.f},{0.f,0.f}};

    const int NT = 2048 / 32;            // 64 tiles per half
    for (int tile = 0; tile < NT; ++tile) {
        // ---- issue next tile's global loads (hidden under compute) ----
        if (tile + 1 < NT) {
            int k0 = (tile + 1) * 32;
            aR  = *(const float4*)(arow_p + k0);
            bL0 = *(const float4*)(w1p0 + k0);  bH0 = *(const float4*)(w1p0 + k0 + 2048);
            bL1 = *(const float4*)(w1p1 + k0);  bH1 = *(const float4*)(w1p1 + k0 + 2048);
            bL2 = *(const float4*)(w1p2 + k0);  bH2 = *(const float4*)(w1p2 + k0 + 2048);
            bL3 = *(const float4*)(w1p3 + k0);  bH3 = *(const float4*)(w1p3 + k0 + 2048);
        }
        // ---- compute current tile (wave's own half) ----
#pragma unroll
        for (int kk = 0; kk < 32; kk += 4) {
            float4 a0 = *(const float4*)(&As[half][eb + 0][kk]);  // wave-uniform
            float4 a1 = *(const float4*)(&As[half][eb + 1][kk]);
            float4 a2 = *(const float4*)(&As[half][eb + 2][kk]);
            float4 a3 = *(const float4*)(&As[half][eb + 3][kk]);
            float bl0 = Bs[half][ln][kk + 0];
            float bl1 = Bs[half][ln][kk + 1];
            float bl2 = Bs[half][ln][kk + 2];
            float bl3 = Bs[half][ln][kk + 3];
            float bh0 = Bs[half][ln + 64][kk + 0];
            float bh1 = Bs[half][ln + 64][kk + 1];
            float bh2 = Bs[half][ln + 64][kk + 2];
            float bh3 = Bs[half][ln + 64][kk + 3];
            acc[0][0] = fmaf(a0.x, bl0, acc[0][0]);
            acc[0][0] = fmaf(a0.y, bl1, acc[0][0]);
            acc[0][0] = fmaf(a0.z, bl2, acc[0][0]);
            acc[0][0] = fmaf(a0.w, bl3, acc[0][0]);
            acc[0][1] = fmaf(a0.x, bh0, acc[0][1]);
            acc[0][1] = fmaf(a0.y, bh1, acc[0][1]);
            acc[0][1] = fmaf(a0.z, bh2, acc[0][1]);
            acc[0][1] = fmaf(a0.w, bh3, acc[0][1]);
            acc[1][0] = fmaf(a1.x, bl0, acc[1][0]);
            acc[1][0] = fmaf(a1.y, bl1, acc[1][0]);
            acc[1][0] = fmaf(a1.z, bl2, acc[1][0]);
            acc[1][0] = fmaf(a1.w, bl3, acc[1][0]);
            acc[1][1] = fmaf(a1.x, bh0, acc[1][1]);
            acc[1][1] = fmaf(a1.y, bh1, acc[1][1]);
            acc[1][1] = fmaf(a1.z, bh2, acc[1][1]);
            acc[1][1] = fmaf(a1.w, bh3, acc[1][1]);
            acc[2][0] = fmaf(a2.x, bl0, acc[2][0]);
            acc[2][0] = fmaf(a2.y, bl1, acc[2][0]);
            acc[2][0] = fmaf(a2.z, bl2, acc[2][0]);
            acc[2][0] = fmaf(a2.w, bl3, acc[2][0]);
            acc[2][1] = fmaf(a2.x, bh0, acc[2][1]);
            acc[2][1] = fmaf(a2.y, bh1, acc[2][1]);
            acc[2][1] = fmaf(a2.z, bh2, acc[2][1]);
            acc[2][1] = fmaf(a2.w, bh3, acc[2][1]);
            acc[3][0] = fmaf(a3.x, bl0, acc[3][0]);
            acc[3][0] = fmaf(a3.y, bl1, acc[3][0]);
            acc[3][0] = fmaf(a3.z, bl2, acc[3][0]);
            acc[3][0] = fmaf(a3.w, bl3, acc[3][0]);
            acc[3][1] = fmaf(a3.x, bh0, acc[3][1]);
            acc[3][1] = fmaf(a3.y, bh1, acc[3][1]);
            acc[3][1] = fmaf(a3.z, bh2, acc[3][1]);
            acc[3][1] = fmaf(a3.w, bh3, acc[3][1]);
        }
        __syncthreads();   // all waves done reading the buffer
        // ---- write next tile ----
        if (tile + 1 < NT) {
            if (aact) *(float4*)(&As[ah][ae][acol]) = aR;
            STB(0, bL0, bL1, bL2, bL3)
            STB(1, bH0, bH1, bH2, bH3)
        }
        __syncthreads();   // buffer ready for next compute
    }
#undef STB

    // ---- stage partials ----
#pragma unroll
    for (int j = 0; j < 4; ++j) {
        hpart[half][eb + j][ln]      = acc[j][0];
        hpart[half][eb + j][ln + 64] = acc[j][1];
    }
    __syncthreads();
    // ---- combine halves + b1 + relu, then exact legacy-order second layer ----
    if (t < GBM && b0 + t < n) {
        float s = 0.f;
        for (int c = 0; c < 32; ++c) {
            float p = 0.f;
#pragma unroll
            for (int q = 0; q < 4; ++q) {
                int nn = 4 * c + q;
                float h = fmaxf(hpart[0][t][nn] + hpart[1][t][nn] + b1[nn], 0.f);
                p = fmaf(h, W2[nn], p);
            }
            s += p;
        }
        float logit = s + b2[0];
        float attn  = 1.f / (1.f + expf(-logit));
        wout[elds[t]] = attn;
        ((int*)&rec[b0 + t])[3] = __float_as_int(attn);
    }
}

// ---------------------------------------------------------------------------
// Kernel 7: connected-component labels of the masked-edge graph (compact ids).
// ---------------------------------------------------------------------------
__global__ __launch_bounds__(1024) void label_kernel(
        const int4* __restrict__ rec, const int* __restrict__ nmask,
        int* __restrict__ lbl) {
    extern __shared__ int L[];        // NSLOTS labels + flag at L[NSLOTS]
    int t = threadIdx.x;
    int n = *nmask;
    for (int c = t; c < NSLOTS; c += 1024) L[c] = c;
    __syncthreads();
    for (;;) {
        if (t == 0) L[NSLOTS] = 0;
        __syncthreads();
        for (int e = t; e < n; e += 1024) {
            int4 r = rec[e];
            int a = L[r.x], b = L[r.y];
            if (a < b)      { atomicMin(&L[r.y], a); L[NSLOTS] = 1; }
            else if (b < a) { atomicMin(&L[r.x], b); L[NSLOTS] = 1; }
        }
        __syncthreads();
        if (!L[NSLOTS]) break;
        __syncthreads();
        for (int c = t; c < NSLOTS; c += 1024) {
            int q  = L[c];
            int qq = L[q];
            if (qq < q) L[c] = qq;
        }
        __syncthreads();
    }
    __syncthreads();
    for (int c = t; c < NSLOTS; c += 1024) lbl[c] = L[c];
}

// ---------------------------------------------------------------------------
// Kernel 8: stable grouping of masked edges by CC label (bitonic sort).
// ---------------------------------------------------------------------------
__global__ __launch_bounds__(1024) void sortgroup_kernel(
        const int4* __restrict__ rec, const int* __restrict__ nmask,
        const int* __restrict__ lbl, int4* __restrict__ srec,
        int* __restrict__ compStart, int* __restrict__ ncompOut) {
    extern __shared__ char sm[];
    int2* a          = (int2*)sm;                        // 64 KB
    unsigned char* hd = (unsigned char*)(sm + 65536);    //  8 KB
    int* part        = (int*)(sm + 65536 + 8192);        //  4 KB
    int t = threadIdx.x;
    int n = *nmask;

    for (int i = t; i < SORTN; i += 1024) {
        int key = 0x7FFFFFFF;
        if (i < n) key = (lbl[rec[i].x] << 13) | i;
        a[i] = make_int2(key, i);
    }
    for (int k = 2; k <= SORTN; k <<= 1) {
        for (int j = k >> 1; j > 0; j >>= 1) {
            __syncthreads();
            for (int i = t; i < SORTN; i += 1024) {
                int ixj = i ^ j;
                if (ixj > i) {
                    int2 ai = a[i], aj = a[ixj];
                    bool up = ((i & k) == 0);
                    if ((ai.x > aj.x) == up) { a[i] = aj; a[ixj] = ai; }
                }
            }
        }
    }
    __syncthreads();
    for (int i = t; i < SORTN; i += 1024) {
        int h = 0;
        if (i < n) {
            srec[i] = rec[a[i].y];
            int l  = a[i].x >> 13;
            int lp = (i == 0) ? -1 : (a[i - 1].x >> 13);
            h = (l != lp) ? 1 : 0;
        }
        hd[i] = (unsigned char)h;
    }
    __syncthreads();
    int base = t * 8;
    int s = 0;
#pragma unroll
    for (int q = 0; q < 8; ++q) s += hd[base + q];
    part[t] = s;
    __syncthreads();
    for (int off = 1; off < 1024; off <<= 1) {
        int mine  = part[t];
        int other = (t >= off) ? part[t - off] : 0;
        __syncthreads();
        part[t] = mine + other;
        __syncthreads();
    }
    int total = part[1023];
    int run = part[t] - s;
#pragma unroll
    for (int q = 0; q < 8; ++q) {
        if (hd[base + q]) { compStart[run] = base + q; ++run; }
    }
    if (t == 0)    *ncompOut = total;
    if (t == 1023) compStart[total] = n;
}

// ---------------------------------------------------------------------------
// Kernel 9: exact union-find, parallel over connected components.
// ---------------------------------------------------------------------------
__global__ __launch_bounds__(256) void uf_kernel(
        const int4* __restrict__ srec, const int* __restrict__ ncompPtr,
        const int* __restrict__ compStart,
        const int* __restrict__ orig, const float* __restrict__ rin,
        int* __restrict__ gpar, float* __restrict__ grank) {
    extern __shared__ char smem[];
    int2* nd = (int2*)smem;    // 128 KB {parent, rank-bits}
    int* ndw = (int*)smem;
    int t = threadIdx.x;
    for (int c = t; c < NSLOTS; c += 256) {
        int o = orig[c];
        float r = (o >= 0) ? rin[o] : 1.0f;
        nd[c] = make_int2(c, __float_as_int(r));
    }
    __syncthreads();

    int ncomp = *ncompPtr;
    for (int c = t; c < ncomp; c += 256) {
        int s  = compStart[c];
        int en = compStart[c + 1];
        for (int j = s; j < en; ++j) {
            int4 r = srec[j];
            int x = r.x, y = r.y;
            float wi = __int_as_float(r.w);
            int p;
            int rx = x;
            while ((p = ndw[rx * 2]) != rx) rx = p;
            int j2 = x;
            while ((p = ndw[j2 * 2]) != rx) { ndw[j2 * 2] = rx; j2 = p; }
            int ry = y;
            while ((p = ndw[ry * 2]) != ry) ry = p;
            j2 = y;
            while ((p = ndw[j2 * 2]) != ry) { ndw[j2 * 2] = ry; j2 = p; }
            if (rx != ry) {
                float ka = __int_as_float(ndw[rx * 2 + 1]);
                float kb = __int_as_float(ndw[ry * 2 + 1]);
                bool bx = ka > kb;
                int big = bx ? rx : ry, small = bx ? ry : rx;
                float nr = bx ? (ka + kb * wi) : (kb + ka * wi);
                ndw[small * 2]   = big;
                ndw[big * 2 + 1] = __float_as_int(nr);
            }
        }
    }
    __syncthreads();
    for (int c = t; c < NSLOTS; c += 256) {
        int2 v = nd[c];
        gpar[c] = v.x;
        grank[c] = __int_as_float(v.y);
    }
}

// ---------------------------------------------------------------------------
// Kernel 10: finalize — per node, claimed -> compact result, else input copy.
// ---------------------------------------------------------------------------
__global__ void finalize_kernel(const int* __restrict__ pin, const float* __restrict__ rin,
                                const int* __restrict__ fo, const int* __restrict__ orig,
                                const int* __restrict__ gpar, const float* __restrict__ grank,
                                float* __restrict__ pout, float* __restrict__ rout) {
    int i = blockIdx.x * blockDim.x + threadIdx.x;
    if (i >= N_NODES) return;
    int c = fo[i];
    float pv, rv;
    if (c != 0x7FFFFFFF) {
        pv = (float)orig[gpar[c]];
        rv = grank[c];
    } else {
        pv = (float)pin[i];
        rv = rin[i];
    }
    pout[i] = pv;
    rout[i] = rv;
}

// ---------------------------------------------------------------------------
extern "C" void kernel_launch(void* const* d_in, const int* in_sizes, int n_in,
                              void* d_out, int out_size, void* d_ws, size_t ws_size,
                              hipStream_t stream) {
    const int*   x_idx = (const int*)d_in[0];
    const int*   y_idx = (const int*)d_in[1];
    const float* xf    = (const float*)d_in[2];
    const float* yf    = (const float*)d_in[3];
    const float* W1    = (const float*)d_in[4];
    const float* b1    = (const float*)d_in[5];
    const float* W2    = (const float*)d_in[6];
    const float* b2    = (const float*)d_in[7];
    const int*   pin   = (const int*)d_in[8];
    const float* rin   = (const float*)d_in[9];

    float* out   = (float*)d_out;
    float* w_out = out;                        // [E]
    float* pout  = out + E_EDGES;              // [N]
    float* rout  = out + E_EDGES + N_NODES;    // [N]

    char* ws = (char*)d_ws;
    float* sim_ws  = (float*)(ws + 0);         //  32768 B
    int*   fo      = (int*)  (ws + 32768);     // 400000 B
    int*   orig    = (int*)  (ws + 432768);    //  65536 B
    int4*  rec     = (int4*) (ws + 498304);    // 131136 B  (8192+4 recs)
    int*   nmask   = (int*)  (ws + 629440);    //     64 B
    int*   gpar    = (int*)  (ws + 629504);    //  65536 B
    float* grank   = (float*)(ws + 695040);    //  65536 B
    int4*  srec    = (int4*) (ws + 760576);    // 131072 B
    int*   compSt  = (int*)  (ws + 891648);    //  32772 B (8193 ints)
    int*   ncomp   = (int*)  (ws + 924424);    //      4 B  -> total ~924 KB
    int*   lbl     = gpar;   // overlay: lbl consumed before uf writes gpar

    // 1) cosine sim
    sim_kernel<<<(E_EDGES * 64) / 256, 256, 0, stream>>>(xf, yf, sim_ws);
    // 2) compact-id mapping + zero w
    int g = (N_NODES + 255) / 256;
    initmap_kernel<<<g, 256, 0, stream>>>(fo, orig, w_out);
    claim_kernel<<<NSLOTS / 256, 256, 0, stream>>>(x_idx, y_idx, fo);
    orig_kernel<<<NSLOTS / 256, 256, 0, stream>>>(x_idx, y_idx, fo, orig);
    // 3) masked-edge compaction (records + padding)
    maskscan_kernel<<<1, 256, 0, stream>>>(x_idx, y_idx, fo, sim_ws, rec, nmask);
    // 4) gate MLP v4 over masked edges only (fills rec.w)
    gate_kernel<<<E_EDGES / GBM, 256, 0, stream>>>(xf, yf, W1, b1, W2, b2, rec, nmask, w_out);
    // 5) CC labels of masked-edge graph (deterministic min-label fixpoint)
    label_kernel<<<1, 1024, (NSLOTS + 1) * sizeof(int), stream>>>(rec, nmask, lbl);
    // 6) stable per-CC grouping (bitonic sort + boundaries)
    sortgroup_kernel<<<1, 1024, 65536 + 8192 + 4096, stream>>>(rec, nmask, lbl,
                                                               srec, compSt, ncomp);
    // 7) exact UF, parallel over components (LDS 128 KB)
    uf_kernel<<<1, 256, 131072, stream>>>(srec, ncomp, compSt, orig, rin, gpar, grank);
    // 8) finalize outputs (base copy + compact scatter fused)
    finalize_kernel<<<g, 256, 0, stream>>>(pin, rin, fo, orig, gpar, grank, pout, rout);
}